// Round 9
// baseline (97.342 us; speedup 1.0000x reference)
//
#include <hip/hip_runtime.h>
#include <math.h>

// Problem constants
#define B_  2
#define S_  2048
#define D_  512
#define H_  8
#define DK_ 64
#define M_  (B_*S_)        // 4096
#define NW   (D_*D_)       // 262144 elems per weight

// q scale: 1/sqrt(DK) * log2(e), so softmax exp(x) becomes exp2(score*sph)
#define QSCALE 0.1803368801111214f

typedef __attribute__((ext_vector_type(8))) short bf16x8;
typedef __attribute__((ext_vector_type(4))) float f32x4;
typedef __attribute__((ext_vector_type(16))) float f32x16;
typedef __attribute__((ext_vector_type(2))) unsigned int u32x2;

__device__ inline unsigned short f2bf(float f) {
    union { float f; unsigned int u; } a; a.f = f;
    unsigned int u = a.u;
    u += 0x7FFFu + ((u >> 16) & 1u);   // RNE
    return (unsigned short)(u >> 16);
}

// scalar pack (NO inline-asm cvt_pk: m240 measured asm variant -37%)
__device__ inline unsigned int pack2(float lo, float hi) {
    return (unsigned int)f2bf(lo) | ((unsigned int)f2bf(hi) << 16);
}

// async global->LDS, 16B per lane. LDS dest must be linear in lane id.
#define GLL(g, l) __builtin_amdgcn_global_load_lds( \
    (const __attribute__((address_space(1))) unsigned int*)(g), \
    (__attribute__((address_space(3))) unsigned int*)(l), 16, 0, 0)

__device__ inline void cvt8(const float* s, unsigned short* d) {
    const float4* sp = (const float4*)s;
    float4 v0 = sp[0], v1 = sp[1];
    union { bf16x8 v; unsigned short s[8]; } u;
    u.s[0]=f2bf(v0.x); u.s[1]=f2bf(v0.y); u.s[2]=f2bf(v0.z); u.s[3]=f2bf(v0.w);
    u.s[4]=f2bf(v1.x); u.s[5]=f2bf(v1.y); u.s[6]=f2bf(v1.z); u.s[7]=f2bf(v1.w);
    *(bf16x8*)d = u.v;
}

__device__ inline void cvtw8(unsigned short* d, float4 v0, float4 v1) {
    union { bf16x8 v; unsigned short s[8]; } u;
    u.s[0]=f2bf(v0.x); u.s[1]=f2bf(v0.y); u.s[2]=f2bf(v0.z); u.s[3]=f2bf(v0.w);
    u.s[4]=f2bf(v1.x); u.s[5]=f2bf(v1.y); u.s[6]=f2bf(v1.z); u.s[7]=f2bf(v1.w);
    *(bf16x8*)d = u.v;
}

// ---------------------------------------------------------------------------
// fp32 -> bf16 for the 4 weight matrices (A-conversion fused into GEMM).
// ---------------------------------------------------------------------------
__global__ __launch_bounds__(256) void cvtw_kernel(
    const float* __restrict__ wq, const float* __restrict__ wk,
    const float* __restrict__ wv, const float* __restrict__ wo,
    unsigned short* __restrict__ WB)
{
    int e = (blockIdx.x * 256 + threadIdx.x) * 8;   // 0 .. 4*NW
    int wi = e >> 18;              // NW = 2^18
    int off = e & (NW - 1);
    const float* src = wi == 0 ? wq : wi == 1 ? wk : wi == 2 ? wv : wo;
    cvt8(src + off, WB + e);
}

// ---------------------------------------------------------------------------
// Fused Q/K/V projection GEMM. A fp32 (reg-staged + converted, 2-deep pipe);
// W bf16 via global_load_lds. Double-buffered, 1 barrier/iter. Grid (192,8).
// ---------------------------------------------------------------------------
__global__ __launch_bounds__(256) void qkv_gemm(
    const float* __restrict__ qF, const float* __restrict__ kF,
    const float* __restrict__ vF, const unsigned short* __restrict__ WB,
    const float* __restrict__ bq, const float* __restrict__ bk, const float* __restrict__ bv,
    unsigned short* __restrict__ q_ws, unsigned short* __restrict__ k_ws,
    unsigned short* __restrict__ vT_ws)
{
    __shared__ unsigned short A_lds[2][64][32];
    __shared__ unsigned short B_lds[2][64][32];

    const int t    = threadIdx.x;
    const int lane = t & 63;
    const int wave = t >> 6;
    const int wm   = wave >> 1, wn = wave & 1;
    const int lrow = lane & 15, lgr = lane >> 4;
    const int seg  = blockIdx.x >> 6;
    const int bm   = blockIdx.x & 63;
    const int bn   = blockIdx.y;

    const float*          A    = seg == 0 ? qF : seg == 1 ? kF : vF;
    const unsigned short* W    = WB + (size_t)seg * NW;
    const float*          bias = seg == 0 ? bq : seg == 1 ? bk : bv;
    unsigned short*       Cp   = seg == 0 ? q_ws : seg == 1 ? k_ws : vT_ws;

    f32x4 acc[2][2] = {};

    const float* Agp = A + (size_t)(bm*64 + (t>>2))*512 + (t&3)*8;
    const unsigned short* Wg = W + (size_t)(bn*64 + (t>>2))*512 + (t&3)*8;
    unsigned short* lA0 = &A_lds[0][t>>2][(t&3)*8];
    unsigned short* lA1 = &A_lds[1][t>>2][(t&3)*8];
    unsigned short* lB0 = &B_lds[0][t>>2][(t&3)*8];
    unsigned short* lB1 = &B_lds[1][t>>2][(t&3)*8];

    float4 a0n = *(const float4*)(Agp);
    float4 a1n = *(const float4*)(Agp + 4);
    GLL(Wg, lB0);
    cvtw8(lA0, a0n, a1n);
    a0n = *(const float4*)(Agp + 32);
    a1n = *(const float4*)(Agp + 36);

    #pragma unroll
    for (int i = 0; i < 16; ++i) {
        __syncthreads();
        const int buf = i & 1;
        if (i < 15) {
            GLL(Wg + (i+1)*32, buf ? lB0 : lB1);
            cvtw8(buf ? lA0 : lA1, a0n, a1n);
        }
        if (i < 14) {
            a0n = *(const float4*)(Agp + (i+2)*32);
            a1n = *(const float4*)(Agp + (i+2)*32 + 4);
        }

        bf16x8 a0 = *(const bf16x8*)&A_lds[buf][wm*32 +      lrow][lgr*8];
        bf16x8 a1 = *(const bf16x8*)&A_lds[buf][wm*32 + 16 + lrow][lgr*8];
        bf16x8 b0 = *(const bf16x8*)&B_lds[buf][wn*32 +      lrow][lgr*8];
        bf16x8 b1 = *(const bf16x8*)&B_lds[buf][wn*32 + 16 + lrow][lgr*8];

        acc[0][0] = __builtin_amdgcn_mfma_f32_16x16x32_bf16(a0, b0, acc[0][0], 0, 0, 0);
        acc[0][1] = __builtin_amdgcn_mfma_f32_16x16x32_bf16(a0, b1, acc[0][1], 0, 0, 0);
        acc[1][0] = __builtin_amdgcn_mfma_f32_16x16x32_bf16(a1, b0, acc[1][0], 0, 0, 0);
        acc[1][1] = __builtin_amdgcn_mfma_f32_16x16x32_bf16(a1, b1, acc[1][1], 0, 0, 0);
    }

    #pragma unroll
    for (int mf = 0; mf < 2; ++mf)
    #pragma unroll
    for (int nf = 0; nf < 2; ++nf)
    #pragma unroll
    for (int r = 0; r < 4; ++r) {
        int grow = bm*64 + wm*32 + mf*16 + lgr*4 + r;
        int gcol = bn*64 + wn*32 + nf*16 + lrow;
        float v = acc[mf][nf][r] + bias[gcol];
        if (seg == 0) v *= QSCALE;
        int bb = grow >> 11, s = grow & 2047;
        int hh = gcol >> 6,  dk = gcol & 63;
        unsigned short bv16 = f2bf(v);
        if (seg < 2)
            Cp[((size_t)(bb*H_ + hh)*S_ + s)*DK_ + dk] = bv16;
        else
            Cp[((size_t)(bb*H_ + hh)*DK_ + dk)*S_ + s] = bv16;
    }
}

// ---------------------------------------------------------------------------
// Output projection GEMM: fp32 out = attn(bf16) @ Wo^T + bo. GLL dbuf.
// ---------------------------------------------------------------------------
__global__ __launch_bounds__(256) void out_gemm(
    const unsigned short* __restrict__ A,
    const unsigned short* __restrict__ W,
    const float* __restrict__ bias,
    float* __restrict__ C)
{
    __shared__ unsigned short A_lds[2][64][32];
    __shared__ unsigned short B_lds[2][64][32];

    const int t    = threadIdx.x;
    const int lane = t & 63;
    const int wave = t >> 6;
    const int wm   = wave >> 1, wn = wave & 1;
    const int lrow = lane & 15, lgr = lane >> 4;
    const int bm   = blockIdx.x, bn = blockIdx.y;

    f32x4 acc[2][2] = {};

    const unsigned short* Ag = A + (size_t)(bm*64 + (t>>2))*512 + (t&3)*8;
    const unsigned short* Wg = W + (size_t)(bn*64 + (t>>2))*512 + (t&3)*8;
    unsigned short* lA0 = &A_lds[0][t>>2][(t&3)*8];
    unsigned short* lA1 = &A_lds[1][t>>2][(t&3)*8];
    unsigned short* lB0 = &B_lds[0][t>>2][(t&3)*8];
    unsigned short* lB1 = &B_lds[1][t>>2][(t&3)*8];

    GLL(Ag, lA0);
    GLL(Wg, lB0);

    for (int kk = 0; kk < 512; kk += 32) {
        const int buf = (kk >> 5) & 1;
        __syncthreads();
        if (kk < 480) {
            GLL(Ag + kk + 32, buf ? lA0 : lA1);
            GLL(Wg + kk + 32, buf ? lB0 : lB1);
        }

        bf16x8 a0 = *(const bf16x8*)&A_lds[buf][wm*32 +      lrow][lgr*8];
        bf16x8 a1 = *(const bf16x8*)&A_lds[buf][wm*32 + 16 + lrow][lgr*8];
        bf16x8 b0 = *(const bf16x8*)&B_lds[buf][wn*32 +      lrow][lgr*8];
        bf16x8 b1 = *(const bf16x8*)&B_lds[buf][wn*32 + 16 + lrow][lgr*8];

        acc[0][0] = __builtin_amdgcn_mfma_f32_16x16x32_bf16(a0, b0, acc[0][0], 0, 0, 0);
        acc[0][1] = __builtin_amdgcn_mfma_f32_16x16x32_bf16(a0, b1, acc[0][1], 0, 0, 0);
        acc[1][0] = __builtin_amdgcn_mfma_f32_16x16x32_bf16(a1, b0, acc[1][0], 0, 0, 0);
        acc[1][1] = __builtin_amdgcn_mfma_f32_16x16x32_bf16(a1, b1, acc[1][1], 0, 0, 0);
    }

    #pragma unroll
    for (int mf = 0; mf < 2; ++mf)
    #pragma unroll
    for (int nf = 0; nf < 2; ++nf)
    #pragma unroll
    for (int r = 0; r < 4; ++r) {
        int grow = bm*64 + wm*32 + mf*16 + lgr*4 + r;
        int gcol = bn*64 + wn*32 + nf*16 + lrow;
        C[(size_t)grow*512 + gcol] = acc[mf][nf][r] + bias[gcol];
    }
}

// ---------------------------------------------------------------------------
// Attention with 32x32x16 MFMA: each wave owns 32 q rows -> K/V LDS read
// traffic per score HALVED vs 16x16 (the measured LDS-pipe bottleneck).
// Both MFMAs swapped: S^T = mfma32(K, Q), O^T = mfma32(V^T, P^T) so each
// lane owns ONE q (lane&31): scalar psum, float4 sph loads, b64 P writes,
// b64 O stores. 4 waves = 2 wq x 2 wh (k-halves), QBLK=64, KVBLK=64,
// no-max softmax via exp2. LDS ~52KB. Grid (32,16) = 512 blocks.
// Layouts: A/B row|col = lane&31, k = 8*(lane>>5)+e;
//          C/D col = lane&31, row = (reg&3)+8*(reg>>2)+4*(lane>>5) [m74/m101].
// ---------------------------------------------------------------------------
__global__ __launch_bounds__(256, 2) void attn32(
    const unsigned short* __restrict__ q_ws,
    const unsigned short* __restrict__ k_ws,
    const unsigned short* __restrict__ vT_ws,
    const float* __restrict__ sph,
    unsigned short* __restrict__ attn_ws)
{
    __shared__ unsigned short K_lds[2][64][68];   // [half][k_row][dk]
    __shared__ unsigned short V_lds[2][64][68];   // [half][dk][k]
    __shared__ unsigned short P_lds[4][32][68];   // [wave][q][k]
    __shared__ float l_sh[2][2][32];              // [wq][wh][q]
    // O_sh overlays K_lds (dead after loop): 2*64*33*4 = 16896 <= 17408
    float (*O_sh)[64][33] = (float (*)[64][33])(&K_lds[0][0][0]);

    const int t    = threadIdx.x;
    const int lane = t & 63, wave = t >> 6;       // 4 waves
    const int ql   = lane & 31;                   // lane's q (and k-col / dk row)
    const int hl   = lane >> 5;                   // half-wave
    const int wq = wave & 1;      // q sub-tile (32 rows)
    const int wh = wave >> 1;     // k half
    const int qt = blockIdx.x, bh = blockIdx.y;
    const int b  = bh >> 3;
    const int h  = bh & 7;
    const int qbase = qt * 64;
    const int qg = qbase + wq*32 + ql;            // this lane's global q row
    const size_t head_off = (size_t)bh * S_ * DK_;

    // Q B-frags: col = q = ql, contraction dk = s*16 + hl*8 + e
    bf16x8 qf[4];
    {
        const unsigned short* qp = q_ws + head_off + (size_t)qg*DK_ + hl*8;
        #pragma unroll
        for (int s = 0; s < 4; ++s)
            qf[s] = *(const bf16x8*)(qp + s*16);
    }

    // staging: 256 thr x (32 shorts K + 32 shorts V) per iter
    const int ssh = t >> 7;             // half 0/1
    const int ssr = (t >> 1) & 63;      // row
    const int ssc = (t & 1) * 32;       // 32-short chunk
    const unsigned short* kstage = k_ws  + head_off + ((size_t)ssh*1024 + ssr)*DK_ + ssc;
    const unsigned short* vstage = vT_ws + head_off + (size_t)ssr*S_ + ssh*1024 + ssc;

    // per-lane sph row pointer (q fixed per lane)
    const float* sph_q = sph + (size_t)b*S_*S_ + (size_t)qg*S_ + wh*1024;

    f32x16 acc0 = {};   // O^T rows dk 0..31 block
    f32x16 acc1 = {};   // dk 32..63 block
    float psum = 0.f;

    // prologue: stage tile 0 + sph tile 0
    bf16x8 kr[4], vr[4];
    #pragma unroll
    for (int c = 0; c < 4; ++c) {
        kr[c] = *(const bf16x8*)(kstage + c*8);
        vr[c] = *(const bf16x8*)(vstage + c*8);
    }
    #pragma unroll
    for (int c = 0; c < 4; ++c) {
        *(bf16x8*)&K_lds[ssh][ssr][ssc + c*8] = kr[c];
        *(bf16x8*)&V_lds[ssh][ssr][ssc + c*8] = vr[c];
    }

    float4 sphr[8];     // [kb*4+g] -> k = kb*32 + g*8 + hl*4 + {0..3}
    #pragma unroll
    for (int kb = 0; kb < 2; ++kb)
    #pragma unroll
    for (int g = 0; g < 4; ++g)
        sphr[kb*4+g] = *(const float4*)(sph_q + kb*32 + g*8 + hl*4);

    for (int kt = 0; kt < 16; ++kt) {
        __syncthreads();   // LDS tile kt ready

        if (kt < 15) {     // next-tile K/V register prefetch
            const unsigned short* kp = kstage + (size_t)(kt+1)*64*DK_;
            const unsigned short* vp = vstage + (kt+1)*64;
            #pragma unroll
            for (int c = 0; c < 4; ++c) {
                kr[c] = *(const bf16x8*)(kp + c*8);
                vr[c] = *(const bf16x8*)(vp + c*8);
            }
        }

        // swapped QK^T: S^T[k][q], two 32-k blocks
        f32x16 sct0 = {}, sct1 = {};
        #pragma unroll
        for (int s = 0; s < 4; ++s) {
            bf16x8 kf0 = *(const bf16x8*)&K_lds[wh][     ql][s*16 + hl*8];
            bf16x8 kf1 = *(const bf16x8*)&K_lds[wh][32 + ql][s*16 + hl*8];
            sct0 = __builtin_amdgcn_mfma_f32_32x32x16_bf16(kf0, qf[s], sct0, 0, 0, 0);
            sct1 = __builtin_amdgcn_mfma_f32_32x32x16_bf16(kf1, qf[s], sct1, 0, 0, 0);
        }

        // p = exp2(s*sph); scalar psum; pack -> P_lds[q][k] (b64 writes)
        // reg r of sct[kb] holds k = kb*32 + (r&3) + 8*(r>>2) + 4*hl
        #pragma unroll
        for (int kb = 0; kb < 2; ++kb) {
            #pragma unroll
            for (int g = 0; g < 4; ++g) {
                float4 sv = sphr[kb*4+g];
                float s0 = kb ? sct1[g*4+0] : sct0[g*4+0];
                float s1 = kb ? sct1[g*4+1] : sct0[g*4+1];
                float s2 = kb ? sct1[g*4+2] : sct0[g*4+2];
                float s3 = kb ? sct1[g*4+3] : sct0[g*4+3];
                float p0 = __builtin_amdgcn_exp2f(s0 * sv.x);
                float p1 = __builtin_amdgcn_exp2f(s1 * sv.y);
                float p2 = __builtin_amdgcn_exp2f(s2 * sv.z);
                float p3 = __builtin_amdgcn_exp2f(s3 * sv.w);
                psum += (p0 + p1) + (p2 + p3);
                u32x2 w;
                w.x = pack2(p0, p1);
                w.y = pack2(p2, p3);
                *(u32x2*)&P_lds[wave][ql][kb*32 + g*8 + hl*4] = w;
            }
        }

        if (kt < 15) {     // next-tile sph prefetch (hides under PV)
            #pragma unroll
            for (int kb = 0; kb < 2; ++kb)
            #pragma unroll
            for (int g = 0; g < 4; ++g)
                sphr[kb*4+g] = *(const float4*)(sph_q + (kt+1)*64 + kb*32 + g*8 + hl*4);
        }

        // PV: O^T[dk][q] += V^T[dk][k] * P[q][k]^T
        #pragma unroll
        for (int s = 0; s < 4; ++s) {
            bf16x8 pf  = *(const bf16x8*)&P_lds[wave][ql][s*16 + hl*8];
            bf16x8 vf0 = *(const bf16x8*)&V_lds[wh][     ql][s*16 + hl*8];
            bf16x8 vf1 = *(const bf16x8*)&V_lds[wh][32 + ql][s*16 + hl*8];
            acc0 = __builtin_amdgcn_mfma_f32_32x32x16_bf16(vf0, pf, acc0, 0, 0, 0);
            acc1 = __builtin_amdgcn_mfma_f32_32x32x16_bf16(vf1, pf, acc1, 0, 0, 0);
        }
        __syncthreads();   // all K/V_lds reads done

        if (kt < 15) {
            #pragma unroll
            for (int c = 0; c < 4; ++c) {
                *(bf16x8*)&K_lds[ssh][ssr][ssc + c*8] = kr[c];
                *(bf16x8*)&V_lds[ssh][ssr][ssc + c*8] = vr[c];
            }
        }
    }

    // row-sum: lanes l and l^32 hold complementary k-halves for q = ql
    psum += __shfl_xor(psum, 32, 64);
    if (lane < 32)
        l_sh[wq][wh][lane] = psum;
    __syncthreads();

    const float linv = 1.f / (l_sh[wq][0][ql] + l_sh[wq][1][ql]);

    if (wh == 1) {
        #pragma unroll
        for (int r = 0; r < 16; ++r) {
            int dk = (r&3) + 8*(r>>2) + 4*hl;
            O_sh[wq][dk     ][ql] = acc0[r];
            O_sh[wq][dk + 32][ql] = acc1[r];
        }
    }
    __syncthreads();
    if (wh == 0) {
        unsigned short* op = attn_ws + ((size_t)(b*S_) + qg)*D_ + h*64;
        #pragma unroll
        for (int vb = 0; vb < 2; ++vb)
        #pragma unroll
        for (int g = 0; g < 4; ++g) {
            int dk0 = vb*32 + g*8 + hl*4;
            float o0 = ((vb ? acc1[g*4+0] : acc0[g*4+0]) + O_sh[wq][dk0+0][ql]) * linv;
            float o1 = ((vb ? acc1[g*4+1] : acc0[g*4+1]) + O_sh[wq][dk0+1][ql]) * linv;
            float o2 = ((vb ? acc1[g*4+2] : acc0[g*4+2]) + O_sh[wq][dk0+2][ql]) * linv;
            float o3 = ((vb ? acc1[g*4+3] : acc0[g*4+3]) + O_sh[wq][dk0+3][ql]) * linv;
            u32x2 w;
            w.x = pack2(o0, o1);
            w.y = pack2(o2, o3);
            *(u32x2*)(op + dk0) = w;
        }
    }
}

// ---------------------------------------------------------------------------
// Fallback attention (proven): 8 waves, in-block split-K, pad-68, exp2.
// ---------------------------------------------------------------------------
__global__ __launch_bounds__(512, 4) void attn_fast8(
    const unsigned short* __restrict__ q_ws,
    const unsigned short* __restrict__ k_ws,
    const unsigned short* __restrict__ vT_ws,
    const float* __restrict__ sph,
    unsigned short* __restrict__ attn_ws)
{
    __shared__ unsigned short K_lds[2][64][68];
    __shared__ unsigned short V_lds[2][64][68];
    __shared__ unsigned short P_lds[8][16][68];
    __shared__ float l_sh[8][16];
    float (*O_sh)[16][68] = (float (*)[16][68])(&K_lds[0][0][0]);

    const int t    = threadIdx.x;
    const int lane = t & 63, wave = t >> 6;
    const int lrow = lane & 15, lgr = lane >> 4;
    const int wq = wave & 3;
    const int wh = wave >> 2;
    const int qt = blockIdx.x, bh = blockIdx.y;
    const int b  = bh >> 3;
    const int h  = bh & 7;
    const int qbase = qt * 64;
    const size_t head_off = (size_t)bh * S_ * DK_;

    bf16x8 qf0, qf1;
    {
        const unsigned short* qp =
            q_ws + head_off + (size_t)(qbase + wq*16 + lrow)*DK_ + lgr*8;
        qf0 = *(const bf16x8*)qp;
        qf1 = *(const bf16x8*)(qp + 32);
    }

    const int sh = t >> 8;
    const int sr = (t >> 2) & 63;
    const int sc = (t & 3) * 16;
    const unsigned short* kstage = k_ws  + head_off + ((size_t)sh*1024 + sr)*DK_ + sc;
    const unsigned short* vstage = vT_ws + head_off + (size_t)sr*S_ + sh*1024 + sc;

    const float* sphb   = sph + (size_t)b * S_ * S_;
    const float* sph_p0 = sphb + (size_t)(qbase + wq*16 + lgr*4 + 0)*S_ + wh*1024 + lrow;
    const float* sph_p1 = sph_p0 + S_;
    const float* sph_p2 = sph_p0 + 2*S_;
    const float* sph_p3 = sph_p0 + 3*S_;

    f32x4 acc_o[4] = {};
    float psum[4] = {0.f, 0.f, 0.f, 0.f};

    bf16x8 kr0 = *(const bf16x8*)(kstage);
    bf16x8 kr1 = *(const bf16x8*)(kstage + 8);
    bf16x8 vr0 = *(const bf16x8*)(vstage);
    bf16x8 vr1 = *(const bf16x8*)(vstage + 8);
    *(bf16x8*)&K_lds[sh][sr][sc]     = kr0;
    *(bf16x8*)&K_lds[sh][sr][sc + 8] = kr1;
    *(bf16x8*)&V_lds[sh][sr][sc]     = vr0;
    *(bf16x8*)&V_lds[sh][sr][sc + 8] = vr1;

    float sphr[4][4];
    #pragma unroll
    for (int nf = 0; nf < 4; ++nf) {
        sphr[nf][0] = sph_p0[nf*16];
        sphr[nf][1] = sph_p1[nf*16];
        sphr[nf][2] = sph_p2[nf*16];
        sphr[nf][3] = sph_p3[nf*16];
    }

    for (int kt = 0; kt < 16; ++kt) {
        __syncthreads();

        if (kt < 15) {
            const unsigned short* kp = kstage + (size_t)(kt+1)*64*DK_;
            const unsigned short* vp = vstage + (kt+1)*64;
            kr0 = *(const bf16x8*)(kp);
            kr1 = *(const bf16x8*)(kp + 8);
            vr0 = *(const bf16x8*)(vp);
            vr1 = *(const bf16x8*)(vp + 8);
        }

        f32x4 sc4[4];
        #pragma unroll
        for (int nf = 0; nf < 4; ++nf) {
            bf16x8 kf0 = *(const bf16x8*)&K_lds[wh][nf*16 + lrow][lgr*8];
            bf16x8 kf1 = *(const bf16x8*)&K_lds[wh][nf*16 + lrow][32 + lgr*8];
            f32x4 a = {};
            a = __builtin_amdgcn_mfma_f32_16x16x32_bf16(qf0, kf0, a, 0, 0, 0);
            a = __builtin_amdgcn_mfma_f32_16x16x32_bf16(qf1, kf1, a, 0, 0, 0);
            sc4[nf] = a;
        }

        #pragma unroll
        for (int nf = 0; nf < 4; ++nf)
        #pragma unroll
        for (int r = 0; r < 4; ++r) {
            float p = __builtin_amdgcn_exp2f(sc4[nf][r] * sphr[nf][r]);
            sc4[nf][r] = p;
            psum[r] += p;
        }

        #pragma unroll
        for (int nf = 0; nf < 4; ++nf)
        #pragma unroll
        for (int r = 0; r < 4; ++r)
            P_lds[wave][lgr*4 + r][nf*16 + lrow] = f2bf(sc4[nf][r]);

        if (kt < 15) {
            const int off = (kt + 1) * 64;
            #pragma unroll
            for (int nf = 0; nf < 4; ++nf) {
                sphr[nf][0] = sph_p0[off + nf*16];
                sphr[nf][1] = sph_p1[off + nf*16];
                sphr[nf][2] = sph_p2[off + nf*16];
                sphr[nf][3] = sph_p3[off + nf*16];
            }
        }

        #pragma unroll
        for (int ks2 = 0; ks2 < 2; ++ks2) {
            bf16x8 pf = *(const bf16x8*)&P_lds[wave][lrow][ks2*32 + lgr*8];
            #pragma unroll
            for (int nb = 0; nb < 4; ++nb) {
                bf16x8 vf = *(const bf16x8*)&V_lds[wh][nb*16 + lrow][ks2*32 + lgr*8];
                acc_o[nb] = __builtin_amdgcn_mfma_f32_16x16x32_bf16(pf, vf, acc_o[nb], 0, 0, 0);
            }
        }
        __syncthreads();

        if (kt < 15) {
            *(bf16x8*)&K_lds[sh][sr][sc]     = kr0;
            *(bf16x8*)&K_lds[sh][sr][sc + 8] = kr1;
            *(bf16x8*)&V_lds[sh][sr][sc]     = vr0;
            *(bf16x8*)&V_lds[sh][sr][sc + 8] = vr1;
        }
    }

    #pragma unroll
    for (int off = 1; off < 16; off <<= 1)
        #pragma unroll
        for (int r = 0; r < 4; ++r)
            psum[r] += __shfl_xor(psum[r], off, 64);

    if (lrow == 0) {
        #pragma unroll
        for (int r = 0; r < 4; ++r)
            l_sh[wave][lgr*4 + r] = psum[r];
    }
    __syncthreads();

    float linv[4];
    #pragma unroll
    for (int r = 0; r < 4; ++r) {
        int row = lgr*4 + r;
        linv[r] = 1.f / (l_sh[wq][row] + l_sh[wq + 4][row]);
    }
    if (wh == 1) {
        #pragma unroll
        for (int nb = 0; nb < 4; ++nb)
        #pragma unroll
        for (int r = 0; r < 4; ++r)
            O_sh[wq][lgr*4 + r][nb*16 + lrow] = acc_o[nb][r];
    }
    __syncthreads();
    if (wh == 0) {
        #pragma unroll
        for (int nb = 0; nb < 4; ++nb)
        #pragma unroll
        for (int r = 0; r < 4; ++r) {
            int qrow = qbase + wq*16 + lgr*4 + r;
            float o = (acc_o[nb][r] + O_sh[wq][lgr*4 + r][nb*16 + lrow]) * linv[r];
            attn_ws[((size_t)(b*S_) + qrow)*D_ + h*64 + nb*16 + lrow] = f2bf(o);
        }
    }
}

// ---------------------------------------------------------------------------
extern "C" void kernel_launch(void* const* d_in, const int* in_sizes, int n_in,
                              void* d_out, int out_size, void* d_ws, size_t ws_size,
                              hipStream_t stream) {
    (void)in_sizes; (void)n_in; (void)out_size;
    const float* query = (const float*)d_in[0];
    const float* key_  = (const float*)d_in[1];
    const float* value = (const float*)d_in[2];
    const float* sph   = (const float*)d_in[3];
    const float* Wq = (const float*)d_in[4];
    const float* bq = (const float*)d_in[5];
    const float* Wk = (const float*)d_in[6];
    const float* bk = (const float*)d_in[7];
    const float* Wv = (const float*)d_in[8];
    const float* bv = (const float*)d_in[9];
    const float* Wo = (const float*)d_in[10];
    const float* bo = (const float*)d_in[11];

    char* ws = (char*)d_ws;
    const size_t MB = 1024*1024;

    // layout: [0 WB(2)][2 q_ws(4)][6 k_ws(4)][10 vT_ws(4)][14 attn_ws(4)] = 18MB
    unsigned short* WB      = (unsigned short*)(ws);
    unsigned short* q_ws    = (unsigned short*)(ws + 2*MB);
    unsigned short* k_ws    = (unsigned short*)(ws + 6*MB);
    unsigned short* vT_ws   = (unsigned short*)(ws + 10*MB);
    unsigned short* attn_ws = (unsigned short*)(ws + 14*MB);

    cvtw_kernel<<<512, 256, 0, stream>>>(Wq, Wk, Wv, Wo, WB);
    qkv_gemm<<<dim3(192, 8), 256, 0, stream>>>(query, key_, value, WB, bq, bk, bv,
                                               q_ws, k_ws, vT_ws);
    if (ws_size >= 18*MB) {
        attn32<<<dim3(S_/64, B_*H_), 256, 0, stream>>>(q_ws, k_ws, vT_ws, sph, attn_ws);
    } else {
        attn_fast8<<<dim3(S_/64, B_*H_), 512, 0, stream>>>(q_ws, k_ws, vT_ws, sph, attn_ws);
    }
    out_gemm<<<dim3(64, 8), 256, 0, stream>>>(attn_ws, WB + 3*(size_t)NW, bo, (float*)d_out);
}

// Round 10
// 84.890 us; speedup vs baseline: 1.1467x; 1.1467x over previous
//
#include <hip/hip_runtime.h>
#include <math.h>

// Problem constants
#define B_  2
#define S_  2048
#define D_  512
#define H_  8
#define DK_ 64
#define M_  (B_*S_)        // 4096
#define NW   (D_*D_)       // 262144 elems per weight

// q scale: 1/sqrt(DK) * log2(e), so softmax exp(x) becomes exp2(score*sph)
#define QSCALE 0.1803368801111214f

typedef __attribute__((ext_vector_type(8))) short bf16x8;
typedef __attribute__((ext_vector_type(4))) float f32x4;

__device__ inline unsigned short f2bf(float f) {
    union { float f; unsigned int u; } a; a.f = f;
    unsigned int u = a.u;
    u += 0x7FFFu + ((u >> 16) & 1u);   // RNE
    return (unsigned short)(u >> 16);
}

// async global->LDS, 16B per lane. LDS dest must be linear in lane id.
#define GLL(g, l) __builtin_amdgcn_global_load_lds( \
    (const __attribute__((address_space(1))) unsigned int*)(g), \
    (__attribute__((address_space(3))) unsigned int*)(l), 16, 0, 0)

__device__ inline void cvt8(const float* s, unsigned short* d) {
    const float4* sp = (const float4*)s;
    float4 v0 = sp[0], v1 = sp[1];
    union { bf16x8 v; unsigned short s[8]; } u;
    u.s[0]=f2bf(v0.x); u.s[1]=f2bf(v0.y); u.s[2]=f2bf(v0.z); u.s[3]=f2bf(v0.w);
    u.s[4]=f2bf(v1.x); u.s[5]=f2bf(v1.y); u.s[6]=f2bf(v1.z); u.s[7]=f2bf(v1.w);
    *(bf16x8*)d = u.v;
}

__device__ inline void cvtw8(unsigned short* d, float4 v0, float4 v1) {
    union { bf16x8 v; unsigned short s[8]; } u;
    u.s[0]=f2bf(v0.x); u.s[1]=f2bf(v0.y); u.s[2]=f2bf(v0.z); u.s[3]=f2bf(v0.w);
    u.s[4]=f2bf(v1.x); u.s[5]=f2bf(v1.y); u.s[6]=f2bf(v1.z); u.s[7]=f2bf(v1.w);
    *(bf16x8*)d = u.v;
}

// ---------------------------------------------------------------------------
// fp32 -> bf16 for the 4 weight matrices (A-conversion fused into GEMM).
// ---------------------------------------------------------------------------
__global__ __launch_bounds__(256) void cvtw_kernel(
    const float* __restrict__ wq, const float* __restrict__ wk,
    const float* __restrict__ wv, const float* __restrict__ wo,
    unsigned short* __restrict__ WB)
{
    int e = (blockIdx.x * 256 + threadIdx.x) * 8;   // 0 .. 4*NW
    int wi = e >> 18;              // NW = 2^18
    int off = e & (NW - 1);
    const float* src = wi == 0 ? wq : wi == 1 ? wk : wi == 2 ? wv : wo;
    cvt8(src + off, WB + e);
}

// ---------------------------------------------------------------------------
// Fused Q/K/V projection GEMM. A fp32 (reg-staged + converted, 2-deep pipe);
// W bf16 via global_load_lds. Double-buffered, 1 barrier/iter. Grid (192,8).
// ---------------------------------------------------------------------------
__global__ __launch_bounds__(256) void qkv_gemm(
    const float* __restrict__ qF, const float* __restrict__ kF,
    const float* __restrict__ vF, const unsigned short* __restrict__ WB,
    const float* __restrict__ bq, const float* __restrict__ bk, const float* __restrict__ bv,
    unsigned short* __restrict__ q_ws, unsigned short* __restrict__ k_ws,
    unsigned short* __restrict__ vT_ws)
{
    __shared__ unsigned short A_lds[2][64][32];
    __shared__ unsigned short B_lds[2][64][32];

    const int t    = threadIdx.x;
    const int lane = t & 63;
    const int wave = t >> 6;
    const int wm   = wave >> 1, wn = wave & 1;
    const int lrow = lane & 15, lgr = lane >> 4;
    const int seg  = blockIdx.x >> 6;
    const int bm   = blockIdx.x & 63;
    const int bn   = blockIdx.y;

    const float*          A    = seg == 0 ? qF : seg == 1 ? kF : vF;
    const unsigned short* W    = WB + (size_t)seg * NW;
    const float*          bias = seg == 0 ? bq : seg == 1 ? bk : bv;
    unsigned short*       Cp   = seg == 0 ? q_ws : seg == 1 ? k_ws : vT_ws;

    f32x4 acc[2][2] = {};

    const float* Agp = A + (size_t)(bm*64 + (t>>2))*512 + (t&3)*8;
    const unsigned short* Wg = W + (size_t)(bn*64 + (t>>2))*512 + (t&3)*8;
    unsigned short* lA0 = &A_lds[0][t>>2][(t&3)*8];
    unsigned short* lA1 = &A_lds[1][t>>2][(t&3)*8];
    unsigned short* lB0 = &B_lds[0][t>>2][(t&3)*8];
    unsigned short* lB1 = &B_lds[1][t>>2][(t&3)*8];

    float4 a0n = *(const float4*)(Agp);
    float4 a1n = *(const float4*)(Agp + 4);
    GLL(Wg, lB0);
    cvtw8(lA0, a0n, a1n);
    a0n = *(const float4*)(Agp + 32);
    a1n = *(const float4*)(Agp + 36);

    #pragma unroll
    for (int i = 0; i < 16; ++i) {
        __syncthreads();
        const int buf = i & 1;
        if (i < 15) {
            GLL(Wg + (i+1)*32, buf ? lB0 : lB1);
            cvtw8(buf ? lA0 : lA1, a0n, a1n);
        }
        if (i < 14) {
            a0n = *(const float4*)(Agp + (i+2)*32);
            a1n = *(const float4*)(Agp + (i+2)*32 + 4);
        }

        bf16x8 a0 = *(const bf16x8*)&A_lds[buf][wm*32 +      lrow][lgr*8];
        bf16x8 a1 = *(const bf16x8*)&A_lds[buf][wm*32 + 16 + lrow][lgr*8];
        bf16x8 b0 = *(const bf16x8*)&B_lds[buf][wn*32 +      lrow][lgr*8];
        bf16x8 b1 = *(const bf16x8*)&B_lds[buf][wn*32 + 16 + lrow][lgr*8];

        acc[0][0] = __builtin_amdgcn_mfma_f32_16x16x32_bf16(a0, b0, acc[0][0], 0, 0, 0);
        acc[0][1] = __builtin_amdgcn_mfma_f32_16x16x32_bf16(a0, b1, acc[0][1], 0, 0, 0);
        acc[1][0] = __builtin_amdgcn_mfma_f32_16x16x32_bf16(a1, b0, acc[1][0], 0, 0, 0);
        acc[1][1] = __builtin_amdgcn_mfma_f32_16x16x32_bf16(a1, b1, acc[1][1], 0, 0, 0);
    }

    #pragma unroll
    for (int mf = 0; mf < 2; ++mf)
    #pragma unroll
    for (int nf = 0; nf < 2; ++nf)
    #pragma unroll
    for (int r = 0; r < 4; ++r) {
        int grow = bm*64 + wm*32 + mf*16 + lgr*4 + r;
        int gcol = bn*64 + wn*32 + nf*16 + lrow;
        float v = acc[mf][nf][r] + bias[gcol];
        if (seg == 0) v *= QSCALE;
        int bb = grow >> 11, s = grow & 2047;
        int hh = gcol >> 6,  dk = gcol & 63;
        unsigned short bv16 = f2bf(v);
        if (seg < 2)
            Cp[((size_t)(bb*H_ + hh)*S_ + s)*DK_ + dk] = bv16;
        else
            Cp[((size_t)(bb*H_ + hh)*DK_ + dk)*S_ + s] = bv16;
    }
}

// ---------------------------------------------------------------------------
// Output projection GEMM: fp32 out = attn(bf16) @ Wo^T + bo. GLL dbuf.
// ---------------------------------------------------------------------------
__global__ __launch_bounds__(256) void out_gemm(
    const unsigned short* __restrict__ A,
    const unsigned short* __restrict__ W,
    const float* __restrict__ bias,
    float* __restrict__ C)
{
    __shared__ unsigned short A_lds[2][64][32];
    __shared__ unsigned short B_lds[2][64][32];

    const int t    = threadIdx.x;
    const int lane = t & 63;
    const int wave = t >> 6;
    const int wm   = wave >> 1, wn = wave & 1;
    const int lrow = lane & 15, lgr = lane >> 4;
    const int bm   = blockIdx.x, bn = blockIdx.y;

    f32x4 acc[2][2] = {};

    const unsigned short* Ag = A + (size_t)(bm*64 + (t>>2))*512 + (t&3)*8;
    const unsigned short* Wg = W + (size_t)(bn*64 + (t>>2))*512 + (t&3)*8;
    unsigned short* lA0 = &A_lds[0][t>>2][(t&3)*8];
    unsigned short* lA1 = &A_lds[1][t>>2][(t&3)*8];
    unsigned short* lB0 = &B_lds[0][t>>2][(t&3)*8];
    unsigned short* lB1 = &B_lds[1][t>>2][(t&3)*8];

    GLL(Ag, lA0);
    GLL(Wg, lB0);

    for (int kk = 0; kk < 512; kk += 32) {
        const int buf = (kk >> 5) & 1;
        __syncthreads();
        if (kk < 480) {
            GLL(Ag + kk + 32, buf ? lA0 : lA1);
            GLL(Wg + kk + 32, buf ? lB0 : lB1);
        }

        bf16x8 a0 = *(const bf16x8*)&A_lds[buf][wm*32 +      lrow][lgr*8];
        bf16x8 a1 = *(const bf16x8*)&A_lds[buf][wm*32 + 16 + lrow][lgr*8];
        bf16x8 b0 = *(const bf16x8*)&B_lds[buf][wn*32 +      lrow][lgr*8];
        bf16x8 b1 = *(const bf16x8*)&B_lds[buf][wn*32 + 16 + lrow][lgr*8];

        acc[0][0] = __builtin_amdgcn_mfma_f32_16x16x32_bf16(a0, b0, acc[0][0], 0, 0, 0);
        acc[0][1] = __builtin_amdgcn_mfma_f32_16x16x32_bf16(a0, b1, acc[0][1], 0, 0, 0);
        acc[1][0] = __builtin_amdgcn_mfma_f32_16x16x32_bf16(a1, b0, acc[1][0], 0, 0, 0);
        acc[1][1] = __builtin_amdgcn_mfma_f32_16x16x32_bf16(a1, b1, acc[1][1], 0, 0, 0);
    }

    #pragma unroll
    for (int mf = 0; mf < 2; ++mf)
    #pragma unroll
    for (int nf = 0; nf < 2; ++nf)
    #pragma unroll
    for (int r = 0; r < 4; ++r) {
        int grow = bm*64 + wm*32 + mf*16 + lgr*4 + r;
        int gcol = bn*64 + wn*32 + nf*16 + lrow;
        C[(size_t)grow*512 + gcol] = acc[mf][nf][r] + bias[gcol];
    }
}

// ---------------------------------------------------------------------------
// Attention (PRIMARY): the proven R3 8-wave structure + pad-68 (0 bank
// conflicts) + exp2 no-max softmax (scale folded into Q) + NO setprio
// (lockstep waves: T5 measured negative in this regime).
// 512 threads = 8 waves: wave = wq (4 q sub-tiles of 16 rows) x wh (2
// k-halves). Reg-staged K/V prefetch issued under compute (T14 schedule).
// In-LDS additive merge of the two k-halves at the end (no-max -> exact).
// ---------------------------------------------------------------------------
__global__ __launch_bounds__(512, 4) void attn_fast8(
    const unsigned short* __restrict__ q_ws,
    const unsigned short* __restrict__ k_ws,
    const unsigned short* __restrict__ vT_ws,
    const float* __restrict__ sph,
    unsigned short* __restrict__ attn_ws)
{
    __shared__ unsigned short K_lds[2][64][68];
    __shared__ unsigned short V_lds[2][64][68];
    __shared__ unsigned short P_lds[8][16][68];
    __shared__ float l_sh[8][16];
    // O_sh overlays K_lds (dead after main loop): 4*16*68*4 = 17408 = sizeof(K_lds)
    float (*O_sh)[16][68] = (float (*)[16][68])(&K_lds[0][0][0]);

    const int t    = threadIdx.x;
    const int lane = t & 63, wave = t >> 6;
    const int lrow = lane & 15, lgr = lane >> 4;
    const int wq = wave & 3;      // q sub-tile (16 rows)
    const int wh = wave >> 2;     // k half
    const int qt = blockIdx.x, bh = blockIdx.y;
    const int b  = bh >> 3;
    const int h  = bh & 7;
    const int qbase = qt * 64;
    const size_t head_off = (size_t)bh * S_ * DK_;

    bf16x8 qf0, qf1;
    {
        const unsigned short* qp =
            q_ws + head_off + (size_t)(qbase + wq*16 + lrow)*DK_ + lgr*8;
        qf0 = *(const bf16x8*)qp;
        qf1 = *(const bf16x8*)(qp + 32);
    }

    const int sh = t >> 8;
    const int sr = (t >> 2) & 63;
    const int sc = (t & 3) * 16;
    const unsigned short* kstage = k_ws  + head_off + ((size_t)sh*1024 + sr)*DK_ + sc;
    const unsigned short* vstage = vT_ws + head_off + (size_t)sr*S_ + sh*1024 + sc;

    const float* sphb   = sph + (size_t)b * S_ * S_;
    const float* sph_p0 = sphb + (size_t)(qbase + wq*16 + lgr*4 + 0)*S_ + wh*1024 + lrow;
    const float* sph_p1 = sph_p0 + S_;
    const float* sph_p2 = sph_p0 + 2*S_;
    const float* sph_p3 = sph_p0 + 3*S_;

    f32x4 acc_o[4] = {};
    float psum[4] = {0.f, 0.f, 0.f, 0.f};

    // prologue: stage tile 0 + sph tile 0
    bf16x8 kr0 = *(const bf16x8*)(kstage);
    bf16x8 kr1 = *(const bf16x8*)(kstage + 8);
    bf16x8 vr0 = *(const bf16x8*)(vstage);
    bf16x8 vr1 = *(const bf16x8*)(vstage + 8);
    *(bf16x8*)&K_lds[sh][sr][sc]     = kr0;
    *(bf16x8*)&K_lds[sh][sr][sc + 8] = kr1;
    *(bf16x8*)&V_lds[sh][sr][sc]     = vr0;
    *(bf16x8*)&V_lds[sh][sr][sc + 8] = vr1;

    float sphr[4][4];
    #pragma unroll
    for (int nf = 0; nf < 4; ++nf) {
        sphr[nf][0] = sph_p0[nf*16];
        sphr[nf][1] = sph_p1[nf*16];
        sphr[nf][2] = sph_p2[nf*16];
        sphr[nf][3] = sph_p3[nf*16];
    }

    for (int kt = 0; kt < 16; ++kt) {
        __syncthreads();   // LDS tile kt ready

        if (kt < 15) {     // next-tile K/V register prefetch (hides under compute)
            const unsigned short* kp = kstage + (size_t)(kt+1)*64*DK_;
            const unsigned short* vp = vstage + (kt+1)*64;
            kr0 = *(const bf16x8*)(kp);
            kr1 = *(const bf16x8*)(kp + 8);
            vr0 = *(const bf16x8*)(vp);
            vr1 = *(const bf16x8*)(vp + 8);
        }

        // QK^T: 16 q rows x 64 k cols per wave
        f32x4 sc4[4];
        #pragma unroll
        for (int nf = 0; nf < 4; ++nf) {
            bf16x8 kf0 = *(const bf16x8*)&K_lds[wh][nf*16 + lrow][lgr*8];
            bf16x8 kf1 = *(const bf16x8*)&K_lds[wh][nf*16 + lrow][32 + lgr*8];
            f32x4 a = {};
            a = __builtin_amdgcn_mfma_f32_16x16x32_bf16(qf0, kf0, a, 0, 0, 0);
            a = __builtin_amdgcn_mfma_f32_16x16x32_bf16(qf1, kf1, a, 0, 0, 0);
            sc4[nf] = a;
        }

        // p = exp2(score * sph)  (Q pre-scaled by log2e/8); row-sum partials
        #pragma unroll
        for (int nf = 0; nf < 4; ++nf)
        #pragma unroll
        for (int r = 0; r < 4; ++r) {
            float p = __builtin_amdgcn_exp2f(sc4[nf][r] * sphr[nf][r]);
            sc4[nf][r] = p;
            psum[r] += p;
        }

        // P -> bf16 -> per-wave LDS (wave-private: no barrier needed)
        #pragma unroll
        for (int nf = 0; nf < 4; ++nf)
        #pragma unroll
        for (int r = 0; r < 4; ++r)
            P_lds[wave][lgr*4 + r][nf*16 + lrow] = f2bf(sc4[nf][r]);

        if (kt < 15) {     // next-tile sph prefetch (hides under PV)
            const int off = (kt + 1) * 64;
            #pragma unroll
            for (int nf = 0; nf < 4; ++nf) {
                sphr[nf][0] = sph_p0[off + nf*16];
                sphr[nf][1] = sph_p1[off + nf*16];
                sphr[nf][2] = sph_p2[off + nf*16];
                sphr[nf][3] = sph_p3[off + nf*16];
            }
        }

        // PV: acc_o[nb] += P @ V  (unnormalized accumulate)
        #pragma unroll
        for (int ks2 = 0; ks2 < 2; ++ks2) {
            bf16x8 pf = *(const bf16x8*)&P_lds[wave][lrow][ks2*32 + lgr*8];
            #pragma unroll
            for (int nb = 0; nb < 4; ++nb) {
                bf16x8 vf = *(const bf16x8*)&V_lds[wh][nb*16 + lrow][ks2*32 + lgr*8];
                acc_o[nb] = __builtin_amdgcn_mfma_f32_16x16x32_bf16(pf, vf, acc_o[nb], 0, 0, 0);
            }
        }
        __syncthreads();   // all K/V_lds reads done

        if (kt < 15) {
            *(bf16x8*)&K_lds[sh][sr][sc]     = kr0;
            *(bf16x8*)&K_lds[sh][sr][sc + 8] = kr1;
            *(bf16x8*)&V_lds[sh][sr][sc]     = vr0;
            *(bf16x8*)&V_lds[sh][sr][sc + 8] = vr1;
        }
    }

    // one-time row-sum reduce (over the 16 k-col lanes)
    #pragma unroll
    for (int off = 1; off < 16; off <<= 1)
        #pragma unroll
        for (int r = 0; r < 4; ++r)
            psum[r] += __shfl_xor(psum[r], off, 64);

    if (lrow == 0) {
        #pragma unroll
        for (int r = 0; r < 4; ++r)
            l_sh[wave][lgr*4 + r] = psum[r];
    }
    __syncthreads();

    float linv[4];
    #pragma unroll
    for (int r = 0; r < 4; ++r) {
        int row = lgr*4 + r;
        linv[r] = 1.f / (l_sh[wq][row] + l_sh[wq + 4][row]);
    }
    if (wh == 1) {
        #pragma unroll
        for (int nb = 0; nb < 4; ++nb)
        #pragma unroll
        for (int r = 0; r < 4; ++r)
            O_sh[wq][lgr*4 + r][nb*16 + lrow] = acc_o[nb][r];
    }
    __syncthreads();
    if (wh == 0) {
        #pragma unroll
        for (int nb = 0; nb < 4; ++nb)
        #pragma unroll
        for (int r = 0; r < 4; ++r) {
            int qrow = qbase + wq*16 + lgr*4 + r;
            float o = (acc_o[nb][r] + O_sh[wq][lgr*4 + r][nb*16 + lrow]) * linv[r];
            attn_ws[((size_t)(b*S_) + qrow)*D_ + h*64 + nb*16 + lrow] = f2bf(o);
        }
    }
}

// ---------------------------------------------------------------------------
extern "C" void kernel_launch(void* const* d_in, const int* in_sizes, int n_in,
                              void* d_out, int out_size, void* d_ws, size_t ws_size,
                              hipStream_t stream) {
    (void)in_sizes; (void)n_in; (void)out_size; (void)ws_size;
    const float* query = (const float*)d_in[0];
    const float* key_  = (const float*)d_in[1];
    const float* value = (const float*)d_in[2];
    const float* sph   = (const float*)d_in[3];
    const float* Wq = (const float*)d_in[4];
    const float* bq = (const float*)d_in[5];
    const float* Wk = (const float*)d_in[6];
    const float* bk = (const float*)d_in[7];
    const float* Wv = (const float*)d_in[8];
    const float* bv = (const float*)d_in[9];
    const float* Wo = (const float*)d_in[10];
    const float* bo = (const float*)d_in[11];

    char* ws = (char*)d_ws;
    const size_t MB = 1024*1024;

    // layout: [0 WB(2)][2 q_ws(4)][6 k_ws(4)][10 vT_ws(4)][14 attn_ws(4)] = 18MB
    // (ws_size has been >=31MB every round; 18MB path is the only path)
    unsigned short* WB      = (unsigned short*)(ws);
    unsigned short* q_ws    = (unsigned short*)(ws + 2*MB);
    unsigned short* k_ws    = (unsigned short*)(ws + 6*MB);
    unsigned short* vT_ws   = (unsigned short*)(ws + 10*MB);
    unsigned short* attn_ws = (unsigned short*)(ws + 14*MB);

    cvtw_kernel<<<512, 256, 0, stream>>>(Wq, Wk, Wv, Wo, WB);
    qkv_gemm<<<dim3(192, 8), 256, 0, stream>>>(query, key_, value, WB, bq, bk, bv,
                                               q_ws, k_ws, vT_ws);
    attn_fast8<<<dim3(S_/64, B_*H_), 512, 0, stream>>>(q_ws, k_ws, vT_ws, sph, attn_ws);
    out_gemm<<<dim3(64, 8), 256, 0, stream>>>(attn_ws, WB + 3*(size_t)NW, bo, (float*)d_out);
}

// Round 11
// 77.424 us; speedup vs baseline: 1.2572x; 1.0964x over previous
//
#include <hip/hip_runtime.h>
#include <math.h>

// Problem constants
#define B_  2
#define S_  2048
#define D_  512
#define H_  8
#define DK_ 64
#define M_  (B_*S_)        // 4096
#define NW   (D_*D_)       // 262144 elems per weight

typedef __attribute__((ext_vector_type(8))) short bf16x8;
typedef __attribute__((ext_vector_type(4))) float f32x4;

__device__ inline unsigned short f2bf(float f) {
    union { float f; unsigned int u; } a; a.f = f;
    unsigned int u = a.u;
    u += 0x7FFFu + ((u >> 16) & 1u);   // RNE
    return (unsigned short)(u >> 16);
}

// async global->LDS, 16B per lane. LDS dest must be linear in lane id.
#define GLL(g, l) __builtin_amdgcn_global_load_lds( \
    (const __attribute__((address_space(1))) unsigned int*)(g), \
    (__attribute__((address_space(3))) unsigned int*)(l), 16, 0, 0)

__device__ inline void cvtw8(unsigned short* d, float4 v0, float4 v1) {
    union { bf16x8 v; unsigned short s[8]; } u;
    u.s[0]=f2bf(v0.x); u.s[1]=f2bf(v0.y); u.s[2]=f2bf(v0.z); u.s[3]=f2bf(v0.w);
    u.s[4]=f2bf(v1.x); u.s[5]=f2bf(v1.y); u.s[6]=f2bf(v1.z); u.s[7]=f2bf(v1.w);
    *(bf16x8*)d = u.v;
}

// ---------------------------------------------------------------------------
// Fused Q/K/V projection GEMM. BOTH A (activations) and W (weights) are fp32,
// reg-staged + converted in-kernel (2-deep pipe), dbuf LDS, 1 barrier/iter.
// Grid (192, 8): blockIdx.x = seg*64 + row-tile, seg 0/1/2 = q/k/v.
// seg 0: bf16 [B,H,S,DK], scaled 0.125 (1/sqrt(DK)). seg 1: [B,H,S,DK].
// seg 2: bf16 [B,H,DK,S] (V transposed).
// ---------------------------------------------------------------------------
__global__ __launch_bounds__(256) void qkv_gemm(
    const float* __restrict__ qF, const float* __restrict__ kF,
    const float* __restrict__ vF,
    const float* __restrict__ Wq, const float* __restrict__ Wk,
    const float* __restrict__ Wv,
    const float* __restrict__ bq, const float* __restrict__ bk,
    const float* __restrict__ bv,
    unsigned short* __restrict__ q_ws, unsigned short* __restrict__ k_ws,
    unsigned short* __restrict__ vT_ws)
{
    __shared__ unsigned short A_lds[2][64][32];
    __shared__ unsigned short B_lds[2][64][32];

    const int t    = threadIdx.x;
    const int lane = t & 63;
    const int wave = t >> 6;
    const int wm   = wave >> 1, wn = wave & 1;
    const int lrow = lane & 15, lgr = lane >> 4;
    const int seg  = blockIdx.x >> 6;
    const int bm   = blockIdx.x & 63;
    const int bn   = blockIdx.y;

    const float*    A    = seg == 0 ? qF : seg == 1 ? kF : vF;
    const float*    W    = seg == 0 ? Wq : seg == 1 ? Wk : Wv;
    const float*    bias = seg == 0 ? bq : seg == 1 ? bk : bv;
    unsigned short* Cp   = seg == 0 ? q_ws : seg == 1 ? k_ws : vT_ws;

    f32x4 acc[2][2] = {};

    const float* Agp = A + (size_t)(bm*64 + (t>>2))*512 + (t&3)*8;
    const float* Wgp = W + (size_t)(bn*64 + (t>>2))*512 + (t&3)*8;
    unsigned short* lA0 = &A_lds[0][t>>2][(t&3)*8];
    unsigned short* lA1 = &A_lds[1][t>>2][(t&3)*8];
    unsigned short* lB0 = &B_lds[0][t>>2][(t&3)*8];
    unsigned short* lB1 = &B_lds[1][t>>2][(t&3)*8];

    // prologue: tile 0 staged to buf0, tile 1 loads in flight
    float4 a0n = *(const float4*)(Agp);
    float4 a1n = *(const float4*)(Agp + 4);
    float4 w0n = *(const float4*)(Wgp);
    float4 w1n = *(const float4*)(Wgp + 4);
    cvtw8(lA0, a0n, a1n);
    cvtw8(lB0, w0n, w1n);
    a0n = *(const float4*)(Agp + 32);
    a1n = *(const float4*)(Agp + 36);
    w0n = *(const float4*)(Wgp + 32);
    w1n = *(const float4*)(Wgp + 36);

    #pragma unroll
    for (int i = 0; i < 16; ++i) {
        __syncthreads();                         // tile i visible
        const int buf = i & 1;
        if (i < 15) {                            // stage tile i+1 -> buf^1
            cvtw8(buf ? lA0 : lA1, a0n, a1n);
            cvtw8(buf ? lB0 : lB1, w0n, w1n);
        }
        if (i < 14) {                            // issue tile i+2 loads
            a0n = *(const float4*)(Agp + (i+2)*32);
            a1n = *(const float4*)(Agp + (i+2)*32 + 4);
            w0n = *(const float4*)(Wgp + (i+2)*32);
            w1n = *(const float4*)(Wgp + (i+2)*32 + 4);
        }

        bf16x8 a0 = *(const bf16x8*)&A_lds[buf][wm*32 +      lrow][lgr*8];
        bf16x8 a1 = *(const bf16x8*)&A_lds[buf][wm*32 + 16 + lrow][lgr*8];
        bf16x8 b0 = *(const bf16x8*)&B_lds[buf][wn*32 +      lrow][lgr*8];
        bf16x8 b1 = *(const bf16x8*)&B_lds[buf][wn*32 + 16 + lrow][lgr*8];

        acc[0][0] = __builtin_amdgcn_mfma_f32_16x16x32_bf16(a0, b0, acc[0][0], 0, 0, 0);
        acc[0][1] = __builtin_amdgcn_mfma_f32_16x16x32_bf16(a0, b1, acc[0][1], 0, 0, 0);
        acc[1][0] = __builtin_amdgcn_mfma_f32_16x16x32_bf16(a1, b0, acc[1][0], 0, 0, 0);
        acc[1][1] = __builtin_amdgcn_mfma_f32_16x16x32_bf16(a1, b1, acc[1][1], 0, 0, 0);
    }

    #pragma unroll
    for (int mf = 0; mf < 2; ++mf)
    #pragma unroll
    for (int nf = 0; nf < 2; ++nf)
    #pragma unroll
    for (int r = 0; r < 4; ++r) {
        int grow = bm*64 + wm*32 + mf*16 + lgr*4 + r;
        int gcol = bn*64 + wn*32 + nf*16 + lrow;
        float v = acc[mf][nf][r] + bias[gcol];
        if (seg == 0) v *= 0.125f;   // 1/sqrt(DK) folded into Q
        int bb = grow >> 11, s = grow & 2047;
        int hh = gcol >> 6,  dk = gcol & 63;
        unsigned short bv16 = f2bf(v);
        if (seg < 2)
            Cp[((size_t)(bb*H_ + hh)*S_ + s)*DK_ + dk] = bv16;
        else
            Cp[((size_t)(bb*H_ + hh)*DK_ + dk)*S_ + s] = bv16;
    }
}

// ---------------------------------------------------------------------------
// Output projection: fp32 out = attn(bf16) @ Wo^T + bo.
// A via global_load_lds dbuf; Wo fp32 reg-staged + converted in-kernel.
// ---------------------------------------------------------------------------
__global__ __launch_bounds__(256) void out_gemm(
    const unsigned short* __restrict__ A,
    const float* __restrict__ W,
    const float* __restrict__ bias,
    float* __restrict__ C)
{
    __shared__ unsigned short A_lds[2][64][32];
    __shared__ unsigned short B_lds[2][64][32];

    const int t    = threadIdx.x;
    const int lane = t & 63;
    const int wave = t >> 6;
    const int wm   = wave >> 1, wn = wave & 1;
    const int lrow = lane & 15, lgr = lane >> 4;
    const int bm   = blockIdx.x, bn = blockIdx.y;

    f32x4 acc[2][2] = {};

    const unsigned short* Ag = A + (size_t)(bm*64 + (t>>2))*512 + (t&3)*8;
    const float* Wgp = W + (size_t)(bn*64 + (t>>2))*512 + (t&3)*8;
    unsigned short* lA0 = &A_lds[0][t>>2][(t&3)*8];
    unsigned short* lA1 = &A_lds[1][t>>2][(t&3)*8];
    unsigned short* lB0 = &B_lds[0][t>>2][(t&3)*8];
    unsigned short* lB1 = &B_lds[1][t>>2][(t&3)*8];

    GLL(Ag, lA0);
    float4 w0n = *(const float4*)(Wgp);
    float4 w1n = *(const float4*)(Wgp + 4);
    cvtw8(lB0, w0n, w1n);
    w0n = *(const float4*)(Wgp + 32);
    w1n = *(const float4*)(Wgp + 36);

    #pragma unroll
    for (int i = 0; i < 16; ++i) {
        __syncthreads();
        const int buf = i & 1;
        if (i < 15) {
            GLL(Ag + (i+1)*32, buf ? lA0 : lA1);
            cvtw8(buf ? lB0 : lB1, w0n, w1n);
        }
        if (i < 14) {
            w0n = *(const float4*)(Wgp + (i+2)*32);
            w1n = *(const float4*)(Wgp + (i+2)*32 + 4);
        }

        bf16x8 a0 = *(const bf16x8*)&A_lds[buf][wm*32 +      lrow][lgr*8];
        bf16x8 a1 = *(const bf16x8*)&A_lds[buf][wm*32 + 16 + lrow][lgr*8];
        bf16x8 b0 = *(const bf16x8*)&B_lds[buf][wn*32 +      lrow][lgr*8];
        bf16x8 b1 = *(const bf16x8*)&B_lds[buf][wn*32 + 16 + lrow][lgr*8];

        acc[0][0] = __builtin_amdgcn_mfma_f32_16x16x32_bf16(a0, b0, acc[0][0], 0, 0, 0);
        acc[0][1] = __builtin_amdgcn_mfma_f32_16x16x32_bf16(a0, b1, acc[0][1], 0, 0, 0);
        acc[1][0] = __builtin_amdgcn_mfma_f32_16x16x32_bf16(a1, b0, acc[1][0], 0, 0, 0);
        acc[1][1] = __builtin_amdgcn_mfma_f32_16x16x32_bf16(a1, b1, acc[1][1], 0, 0, 0);
    }

    #pragma unroll
    for (int mf = 0; mf < 2; ++mf)
    #pragma unroll
    for (int nf = 0; nf < 2; ++nf)
    #pragma unroll
    for (int r = 0; r < 4; ++r) {
        int grow = bm*64 + wm*32 + mf*16 + lgr*4 + r;
        int gcol = bn*64 + wn*32 + nf*16 + lrow;
        C[(size_t)grow*512 + gcol] = acc[mf][nf][r] + bias[gcol];
    }
}

// ---------------------------------------------------------------------------
// Attention — VERBATIM the R3-measured 48.5us kernel (best of 8 variants):
// 8 waves (4 q-subtiles x 2 k-halves), pad-72 LDS, no-max softmax via __expf
// (Q pre-scaled 0.125), reg-staged K/V prefetch, per-wave P_lds, additive
// in-LDS merge of the two k-halves. No setprio.
// ---------------------------------------------------------------------------
__global__ __launch_bounds__(512, 4) void attn_fast(
    const unsigned short* __restrict__ q_ws,
    const unsigned short* __restrict__ k_ws,
    const unsigned short* __restrict__ vT_ws,
    const float* __restrict__ sph,
    unsigned short* __restrict__ attn_ws)
{
    __shared__ unsigned short K_lds[2][64][72];
    __shared__ unsigned short V_lds[2][64][72];
    __shared__ unsigned short P_lds[8][16][72];
    __shared__ float l_sh[8][16];
    // O_sh overlays K_lds (dead after main loop): 4*16*72*4 = 18432 = sizeof(K_lds)
    float (*O_sh)[16][72] = (float (*)[16][72])(&K_lds[0][0][0]);

    const int t    = threadIdx.x;
    const int lane = t & 63, wave = t >> 6;
    const int lrow = lane & 15, lgr = lane >> 4;
    const int wq = wave & 3;      // q sub-tile (16 rows)
    const int wh = wave >> 2;     // k half
    const int qt = blockIdx.x, bh = blockIdx.y;
    const int b  = bh >> 3;
    const int h  = bh & 7;
    const int qbase = qt * 64;
    const size_t head_off = (size_t)bh * S_ * DK_;

    bf16x8 qf0, qf1;
    {
        const unsigned short* qp =
            q_ws + head_off + (size_t)(qbase + wq*16 + lrow)*DK_ + lgr*8;
        qf0 = *(const bf16x8*)qp;
        qf1 = *(const bf16x8*)(qp + 32);
    }

    const int sh = t >> 8;
    const int sr = (t >> 2) & 63;
    const int sc = (t & 3) * 16;
    const unsigned short* kstage = k_ws  + head_off + ((size_t)sh*1024 + sr)*DK_ + sc;
    const unsigned short* vstage = vT_ws + head_off + (size_t)sr*S_ + sh*1024 + sc;

    const float* sphb   = sph + (size_t)b * S_ * S_;
    const float* sph_p0 = sphb + (size_t)(qbase + wq*16 + lgr*4 + 0)*S_ + wh*1024 + lrow;
    const float* sph_p1 = sph_p0 + S_;
    const float* sph_p2 = sph_p0 + 2*S_;
    const float* sph_p3 = sph_p0 + 3*S_;

    f32x4 acc_o[4] = {};
    float psum[4] = {0.f, 0.f, 0.f, 0.f};

    // prologue: stage tile 0 + sph tile 0
    bf16x8 kr0 = *(const bf16x8*)(kstage);
    bf16x8 kr1 = *(const bf16x8*)(kstage + 8);
    bf16x8 vr0 = *(const bf16x8*)(vstage);
    bf16x8 vr1 = *(const bf16x8*)(vstage + 8);
    *(bf16x8*)&K_lds[sh][sr][sc]     = kr0;
    *(bf16x8*)&K_lds[sh][sr][sc + 8] = kr1;
    *(bf16x8*)&V_lds[sh][sr][sc]     = vr0;
    *(bf16x8*)&V_lds[sh][sr][sc + 8] = vr1;

    float sphr[4][4];
    #pragma unroll
    for (int nf = 0; nf < 4; ++nf) {
        sphr[nf][0] = sph_p0[nf*16];
        sphr[nf][1] = sph_p1[nf*16];
        sphr[nf][2] = sph_p2[nf*16];
        sphr[nf][3] = sph_p3[nf*16];
    }

    for (int kt = 0; kt < 16; ++kt) {
        __syncthreads();   // LDS tile kt ready

        if (kt < 15) {     // next-tile K/V register prefetch
            const unsigned short* kp = kstage + (size_t)(kt+1)*64*DK_;
            const unsigned short* vp = vstage + (kt+1)*64;
            kr0 = *(const bf16x8*)(kp);
            kr1 = *(const bf16x8*)(kp + 8);
            vr0 = *(const bf16x8*)(vp);
            vr1 = *(const bf16x8*)(vp + 8);
        }

        // QK^T: 16 q rows x 64 k cols per wave
        f32x4 sc4[4];
        #pragma unroll
        for (int nf = 0; nf < 4; ++nf) {
            bf16x8 kf0 = *(const bf16x8*)&K_lds[wh][nf*16 + lrow][lgr*8];
            bf16x8 kf1 = *(const bf16x8*)&K_lds[wh][nf*16 + lrow][32 + lgr*8];
            f32x4 a = {};
            a = __builtin_amdgcn_mfma_f32_16x16x32_bf16(qf0, kf0, a, 0, 0, 0);
            a = __builtin_amdgcn_mfma_f32_16x16x32_bf16(qf1, kf1, a, 0, 0, 0);
            sc4[nf] = a;
        }

        // p = exp(score * sph); accumulate per-lane row-sum partials
        #pragma unroll
        for (int nf = 0; nf < 4; ++nf)
        #pragma unroll
        for (int r = 0; r < 4; ++r) {
            float p = __expf(sc4[nf][r] * sphr[nf][r]);
            sc4[nf][r] = p;
            psum[r] += p;
        }

        // P -> bf16 -> per-wave LDS (wave-private: no barrier needed)
        #pragma unroll
        for (int nf = 0; nf < 4; ++nf)
        #pragma unroll
        for (int r = 0; r < 4; ++r)
            P_lds[wave][lgr*4 + r][nf*16 + lrow] = f2bf(sc4[nf][r]);

        if (kt < 15) {     // next-tile sph prefetch (hides under PV)
            const int off = (kt + 1) * 64;
            #pragma unroll
            for (int nf = 0; nf < 4; ++nf) {
                sphr[nf][0] = sph_p0[off + nf*16];
                sphr[nf][1] = sph_p1[off + nf*16];
                sphr[nf][2] = sph_p2[off + nf*16];
                sphr[nf][3] = sph_p3[off + nf*16];
            }
        }

        // PV: acc_o[nb] += P @ V  (unnormalized accumulate)
        #pragma unroll
        for (int ks2 = 0; ks2 < 2; ++ks2) {
            bf16x8 pf = *(const bf16x8*)&P_lds[wave][lrow][ks2*32 + lgr*8];
            #pragma unroll
            for (int nb = 0; nb < 4; ++nb) {
                bf16x8 vf = *(const bf16x8*)&V_lds[wh][nb*16 + lrow][ks2*32 + lgr*8];
                acc_o[nb] = __builtin_amdgcn_mfma_f32_16x16x32_bf16(pf, vf, acc_o[nb], 0, 0, 0);
            }
        }
        __syncthreads();   // all K/V_lds reads done

        if (kt < 15) {
            *(bf16x8*)&K_lds[sh][sr][sc]     = kr0;
            *(bf16x8*)&K_lds[sh][sr][sc + 8] = kr1;
            *(bf16x8*)&V_lds[sh][sr][sc]     = vr0;
            *(bf16x8*)&V_lds[sh][sr][sc + 8] = vr1;
        }
    }

    // one-time row-sum reduce (over lrow lanes within each lgr group)
    #pragma unroll
    for (int off = 1; off < 16; off <<= 1)
        #pragma unroll
        for (int r = 0; r < 4; ++r)
            psum[r] += __shfl_xor(psum[r], off, 64);

    if (lrow == 0) {
        #pragma unroll
        for (int r = 0; r < 4; ++r)
            l_sh[wave][lgr*4 + r] = psum[r];
    }
    __syncthreads();

    float linv[4];
    #pragma unroll
    for (int r = 0; r < 4; ++r) {
        int row = lgr*4 + r;
        linv[r] = 1.f / (l_sh[wq][row] + l_sh[wq + 4][row]);
    }
    if (wh == 1) {
        #pragma unroll
        for (int nb = 0; nb < 4; ++nb)
        #pragma unroll
        for (int r = 0; r < 4; ++r)
            O_sh[wq][lgr*4 + r][nb*16 + lrow] = acc_o[nb][r];
    }
    __syncthreads();
    if (wh == 0) {
        #pragma unroll
        for (int nb = 0; nb < 4; ++nb)
        #pragma unroll
        for (int r = 0; r < 4; ++r) {
            int qrow = qbase + wq*16 + lgr*4 + r;
            float o = (acc_o[nb][r] + O_sh[wq][lgr*4 + r][nb*16 + lrow]) * linv[r];
            attn_ws[((size_t)(b*S_) + qrow)*D_ + h*64 + nb*16 + lrow] = f2bf(o);
        }
    }
}

// ---------------------------------------------------------------------------
extern "C" void kernel_launch(void* const* d_in, const int* in_sizes, int n_in,
                              void* d_out, int out_size, void* d_ws, size_t ws_size,
                              hipStream_t stream) {
    (void)in_sizes; (void)n_in; (void)out_size; (void)ws_size;
    const float* query = (const float*)d_in[0];
    const float* key_  = (const float*)d_in[1];
    const float* value = (const float*)d_in[2];
    const float* sph   = (const float*)d_in[3];
    const float* Wq = (const float*)d_in[4];
    const float* bq = (const float*)d_in[5];
    const float* Wk = (const float*)d_in[6];
    const float* bk = (const float*)d_in[7];
    const float* Wv = (const float*)d_in[8];
    const float* bv = (const float*)d_in[9];
    const float* Wo = (const float*)d_in[10];
    const float* bo = (const float*)d_in[11];

    char* ws = (char*)d_ws;
    const size_t MB = 1024*1024;

    // layout: [0 q_ws(4)][4 k_ws(4)][8 vT_ws(4)][12 attn_ws(4)] = 16MB
    unsigned short* q_ws    = (unsigned short*)(ws);
    unsigned short* k_ws    = (unsigned short*)(ws + 4*MB);
    unsigned short* vT_ws   = (unsigned short*)(ws + 8*MB);
    unsigned short* attn_ws = (unsigned short*)(ws + 12*MB);

    qkv_gemm<<<dim3(192, 8), 256, 0, stream>>>(query, key_, value, Wq, Wk, Wv,
                                               bq, bk, bv, q_ws, k_ws, vT_ws);
    attn_fast<<<dim3(S_/64, B_*H_), 512, 0, stream>>>(q_ws, k_ws, vT_ws, sph, attn_ws);
    out_gemm<<<dim3(64, 8), 256, 0, stream>>>(attn_ws, Wo, bo, (float*)d_out);
}